// Round 1
// baseline (389.694 us; speedup 1.0000x reference)
//
#include <hip/hip_runtime.h>

#define NB 8
#define NA 102400
#define NGRID 320
#define NG 16
#define NZ 64
#define NSUP 5
#define NQ 3
#define NCLSF 80.0f

// ws float layout:
// [0..255]   protoSum[4][64]
// [256..259] protoCnt[4]
// [260..267] regSum[8]
// [268..275] nposSum[8]
// [276]      clsSum
// [277]      npqSum

__device__ __forceinline__ void anchor_of(int a, float& ax0, float& ay0,
                                          float& ax1, float& ay1) {
    int i = a / NGRID;
    int j = a - i * NGRID;
    ax0 = (float)j * 4.0f;
    ay0 = (float)i * 4.0f;
    ax1 = ax0 + 4.0f;
    ay1 = ay0 + 4.0f;
}

// Replicates: iou over 16 boxes, first-max argmax, target class assignment.
__device__ __forceinline__ void assign_anchor(const float* __restrict__ ann, int a,
                                              float& tgt, int& arg, float& iou_max) {
    float ax0, ay0, ax1, ay1;
    anchor_of(a, ax0, ay0, ax1, ay1);
    float aw = ax1 - ax0, ah = ay1 - ay0;
    float aarea = aw * ah;
    float best = -1.0f;
    int bi = 0;
    #pragma unroll
    for (int j = 0; j < NG; ++j) {
        float bx0 = ann[j * 5 + 0], by0 = ann[j * 5 + 1];
        float bx1 = ann[j * 5 + 2], by1 = ann[j * 5 + 3];
        float iw = fmaxf(fminf(ax1, bx1) - fmaxf(ax0, bx0), 0.0f);
        float ih = fmaxf(fminf(ay1, by1) - fmaxf(ay0, by0), 0.0f);
        float inter = iw * ih;
        float area = (bx1 - bx0) * (by1 - by0);
        float ua = fmaxf(aarea + area - inter, 1e-8f);
        float iou = inter / ua;
        if (iou > best) { best = iou; bi = j; }   // strict > : first max wins
    }
    iou_max = best;
    arg = bi;
    float lab = ann[bi * 5 + 4];
    tgt = (best >= 0.5f) ? lab : ((best < 0.4f) ? NCLSF : -1.0f);
}

// Kernel A: regression loss partials per image. One thread per (b,a).
__global__ __launch_bounds__(256) void k_reg(const float* __restrict__ annotations,
                                             const float* __restrict__ regressions,
                                             float* __restrict__ ws) {
    int idx = blockIdx.x * 256 + threadIdx.x;
    int b = idx / NA;           // A % 256 == 0 -> whole block in one image
    int a = idx - b * NA;
    const float* ann = annotations + b * NG * 5;
    float tgt; int arg; float im;
    assign_anchor(ann, a, tgt, arg, im);
    float sl1 = 0.0f, posf = 0.0f;
    if (im >= 0.5f) {
        posf = 1.0f;
        float ax0, ay0, ax1, ay1;
        anchor_of(a, ax0, ay0, ax1, ay1);
        float aw = ax1 - ax0, ah = ay1 - ay0;
        float acx = ax0 + 0.5f * aw, acy = ay0 + 0.5f * ah;
        const float* bb = ann + arg * 5;
        float rgw = bb[2] - bb[0], rgh = bb[3] - bb[1];
        float gcx = bb[0] + 0.5f * rgw, gcy = bb[1] + 0.5f * rgh;
        float gw = fmaxf(rgw, 1.0f), gh = fmaxf(rgh, 1.0f);
        float t[4];
        t[0] = ((gcx - acx) / aw) / 0.1f;
        t[1] = ((gcy - acy) / ah) / 0.1f;
        t[2] = logf(gw / aw) / 0.2f;
        t[3] = logf(gh / ah) / 0.2f;
        const float* rg = regressions + (size_t)idx * 4;
        #pragma unroll
        for (int k = 0; k < 4; ++k) {
            float diff = fabsf(t[k] - rg[k]);
            sl1 += (diff <= (1.0f / 9.0f)) ? (0.5f * 9.0f * diff * diff)
                                           : (diff - 0.5f / 9.0f);
        }
    }
    #pragma unroll
    for (int s = 1; s < 64; s <<= 1) {
        sl1 += __shfl_xor(sl1, s, 64);
        posf += __shfl_xor(posf, s, 64);
    }
    __shared__ float s_sl1[4], s_np[4];
    int lane = threadIdx.x & 63, wid = threadIdx.x >> 6;
    if (lane == 0) { s_sl1[wid] = sl1; s_np[wid] = posf; }
    __syncthreads();
    if (threadIdx.x == 0) {
        atomicAdd(&ws[260 + b], s_sl1[0] + s_sl1[1] + s_sl1[2] + s_sl1[3]);
        atomicAdd(&ws[268 + b], s_np[0] + s_np[1] + s_np[2] + s_np[3]);
    }
}

// Kernel B: prototype sums/counts over the 5 support images.
// Each wave: 64-row chunks; lanes compute their row's class, then 16 inner
// iterations of 4 rows x float4/lane coalesced loads.
__global__ __launch_bounds__(256) void k_proto(const float* __restrict__ annotations,
                                               const float* __restrict__ cls,
                                               float* __restrict__ ws) {
    const int NCHUNK = (NSUP * NA) / 64;   // 8000
    int lane = threadIdx.x & 63;
    int rg = lane >> 4;
    int zi = (lane & 15) * 4;
    int gwid = (blockIdx.x * blockDim.x + threadIdx.x) >> 6;
    int nw = (gridDim.x * blockDim.x) >> 6;
    float acc[4][4] = {};
    float cnt[4] = {};
    for (int chunk = gwid; chunk < NCHUNK; chunk += nw) {
        int base = chunk * 64;
        int r = base + lane;
        int b = r / NA;
        int a = r - b * NA;
        float tgt; int arg; float im;
        assign_anchor(annotations + b * NG * 5, a, tgt, arg, im);
        int ci = (tgt == NCLSF) ? 3 : ((tgt >= 0.0f) ? (int)tgt : -1);
        #pragma unroll
        for (int i = 0; i < 16; ++i) {
            int src = i * 4 + rg;
            int cq = __shfl(ci, src, 64);
            const float4 v = *reinterpret_cast<const float4*>(
                cls + (size_t)(base + src) * NZ + zi);
            if (cq == 0)      { acc[0][0]+=v.x; acc[0][1]+=v.y; acc[0][2]+=v.z; acc[0][3]+=v.w; }
            else if (cq == 1) { acc[1][0]+=v.x; acc[1][1]+=v.y; acc[1][2]+=v.z; acc[1][3]+=v.w; }
            else if (cq == 2) { acc[2][0]+=v.x; acc[2][1]+=v.y; acc[2][2]+=v.z; acc[2][3]+=v.w; }
            else if (cq == 3) { acc[3][0]+=v.x; acc[3][1]+=v.y; acc[3][2]+=v.z; acc[3][3]+=v.w; }
            if ((lane & 15) == 0) {
                if (cq == 0) cnt[0] += 1.0f;
                else if (cq == 1) cnt[1] += 1.0f;
                else if (cq == 2) cnt[2] += 1.0f;
                else if (cq == 3) cnt[3] += 1.0f;
            }
        }
    }
    #pragma unroll
    for (int c = 0; c < 4; ++c) {
        #pragma unroll
        for (int k = 0; k < 4; ++k) {
            float v = acc[c][k];
            v += __shfl_xor(v, 16, 64);
            v += __shfl_xor(v, 32, 64);
            if (lane < 16) atomicAdd(&ws[c * NZ + zi + k], v);
        }
        float cv = cnt[c];
        cv += __shfl_xor(cv, 16, 64);
        cv += __shfl_xor(cv, 32, 64);
        if (lane == 0) atomicAdd(&ws[256 + c], cv);
    }
}

// Kernel C: query pass — squared dists to 4 protos, softmax, focal terms.
__global__ __launch_bounds__(256) void k_query(const float* __restrict__ annotations,
                                               const float* __restrict__ cls,
                                               float* __restrict__ ws) {
    const int NCHUNK = (NQ * NA) / 64;     // 4800
    int lane = threadIdx.x & 63;
    int rg = lane >> 4;
    int zi = (lane & 15) * 4;
    float proto[4][4];
    #pragma unroll
    for (int c = 0; c < 4; ++c) {
        float cv = fmaxf(ws[256 + c], 1.0f);
        #pragma unroll
        for (int k = 0; k < 4; ++k)
            proto[c][k] = ws[c * NZ + zi + k] / cv;
    }
    int gwid = (blockIdx.x * blockDim.x + threadIdx.x) >> 6;
    int nw = (gridDim.x * blockDim.x) >> 6;
    float clsAcc = 0.0f, npqAcc = 0.0f;
    for (int chunk = gwid; chunk < NCHUNK; chunk += nw) {
        int base = chunk * 64;
        int r = base + lane;
        int b = NSUP + r / NA;
        int a = r % NA;
        float tgt; int arg; float im;
        assign_anchor(annotations + b * NG * 5, a, tgt, arg, im);
        int vld = (tgt != -1.0f) ? 1 : 0;
        int tix = (tgt == NCLSF) ? 3 : ((tgt == 2.0f) ? 2 : ((tgt == 1.0f) ? 1 : 0));
        int code = tix | (vld << 2);
        #pragma unroll
        for (int i = 0; i < 16; ++i) {
            int src = i * 4 + rg;
            int cq = __shfl(code, src, 64);
            const float4 e = *reinterpret_cast<const float4*>(
                cls + ((size_t)(NSUP * NA) + base + src) * NZ + zi);
            float dd[4];
            #pragma unroll
            for (int c = 0; c < 4; ++c) {
                float t0 = e.x - proto[c][0];
                float t1 = e.y - proto[c][1];
                float t2 = e.z - proto[c][2];
                float t3 = e.w - proto[c][3];
                float s = t0 * t0 + t1 * t1 + t2 * t2 + t3 * t3;
                s += __shfl_xor(s, 1, 64);
                s += __shfl_xor(s, 2, 64);
                s += __shfl_xor(s, 4, 64);
                s += __shfl_xor(s, 8, 64);
                dd[c] = s;
            }
            float m = fminf(fminf(dd[0], dd[1]), fminf(dd[2], dd[3]));
            float ex0 = expf(m - dd[0]);
            float ex1 = expf(m - dd[1]);
            float ex2 = expf(m - dd[2]);
            float ex3 = expf(m - dd[3]);
            float ssum = ex0 + ex1 + ex2 + ex3;
            int tq = cq & 3;
            float pnum = (tq == 0) ? ex0 : (tq == 1) ? ex1 : (tq == 2) ? ex2 : ex3;
            float prob = pnum / ssum;
            float om = 1.0f - prob;
            float term = -0.25f * om * om * logf(prob);
            if ((lane & 15) == 0 && (cq & 4)) {
                clsAcc += term;
                if (tq != 3) npqAcc += 1.0f;
            }
        }
    }
    #pragma unroll
    for (int s = 1; s < 64; s <<= 1) {
        clsAcc += __shfl_xor(clsAcc, s, 64);
        npqAcc += __shfl_xor(npqAcc, s, 64);
    }
    if (lane == 0) {
        atomicAdd(&ws[276], clsAcc);
        atomicAdd(&ws[277], npqAcc);
    }
}

__global__ void k_final(const float* __restrict__ ws, float* __restrict__ out) {
    if (threadIdx.x == 0 && blockIdx.x == 0) {
        float clsl = ws[276] / fmaxf(ws[277], 1.0f);
        float rs = 0.0f;
        #pragma unroll
        for (int b = 0; b < NB; ++b) {
            float np_ = ws[268 + b];
            float sv = ws[260 + b];
            rs += (np_ > 0.0f) ? (sv / fmaxf(4.0f * np_, 1.0f)) : 0.0f;
        }
        out[0] = clsl;          // cls_loss
        out[1] = rs * 0.125f;   // reg_loss (mean over 8 images)
    }
}

extern "C" void kernel_launch(void* const* d_in, const int* in_sizes, int n_in,
                              void* d_out, int out_size, void* d_ws, size_t ws_size,
                              hipStream_t stream) {
    const float* classifications = (const float*)d_in[0];
    const float* regressions    = (const float*)d_in[1];
    // d_in[2] (anchors) is analytic: [4j, 4i, 4j+4, 4i+4] — recomputed on device.
    const float* annotations    = (const float*)d_in[3];
    float* ws  = (float*)d_ws;
    float* out = (float*)d_out;

    hipMemsetAsync(d_ws, 0, 2048, stream);   // 278 floats of scratch
    k_reg<<<(NB * NA) / 256, 256, 0, stream>>>(annotations, regressions, ws);
    k_proto<<<512, 256, 0, stream>>>(annotations, classifications, ws);
    k_query<<<512, 256, 0, stream>>>(annotations, classifications, ws);
    k_final<<<1, 64, 0, stream>>>(ws, out);
}

// Round 2
// 193.059 us; speedup vs baseline: 2.0185x; 2.0185x over previous
//
#include <hip/hip_runtime.h>

#define NB 8
#define NA 102400
#define NGRID 320
#define NG 16
#define NZ 64
#define NSUP 5
#define NQ 3
#define NCLSF 80.0f

// ws float layout:
//  slice s in [0,4): base s*260:
//    [c*64+d]   protoSum partial (256 floats)
//    [256+c]    protoCnt partial (4 floats)
//  [1040..1047] regSum[b]
//  [1048..1055] nposSum[b]
//  [1056..1059] clsSum slices
//  [1060..1063] npqSum slices
// byte offset 8192: uint8 codes[NB*NA]  (bits0-1 = class idx, bit2 = valid)
#define WS_REG   1040
#define WS_NPOS  1048
#define WS_CLS   1056
#define WS_NPQ   1060
#define CODES_OFF 8192
#define WS_BYTES_NEEDED (CODES_OFF + NB * NA)

__device__ __forceinline__ void anchor_of(int a, float& ax0, float& ay0,
                                          float& ax1, float& ay1) {
    int i = a / NGRID;
    int j = a - i * NGRID;
    ax0 = (float)j * 4.0f;
    ay0 = (float)i * 4.0f;
    ax1 = ax0 + 4.0f;
    ay1 = ay0 + 4.0f;
}

// iou over 16 boxes, FIRST-max argmax, target assignment (matches jnp.argmax).
__device__ __forceinline__ void assign_anchor(const float* __restrict__ ann, int a,
                                              float& tgt, int& arg, float& iou_max) {
    float ax0, ay0, ax1, ay1;
    anchor_of(a, ax0, ay0, ax1, ay1);
    float aw = ax1 - ax0, ah = ay1 - ay0;
    float aarea = aw * ah;
    float best = -1.0f;
    int bi = 0;
    #pragma unroll
    for (int j = 0; j < NG; ++j) {
        float bx0 = ann[j * 5 + 0], by0 = ann[j * 5 + 1];
        float bx1 = ann[j * 5 + 2], by1 = ann[j * 5 + 3];
        float iw = fmaxf(fminf(ax1, bx1) - fmaxf(ax0, bx0), 0.0f);
        float ih = fmaxf(fminf(ay1, by1) - fmaxf(ay0, by0), 0.0f);
        float inter = iw * ih;
        float area = (bx1 - bx0) * (by1 - by0);
        float ua = fmaxf(aarea + area - inter, 1e-8f);
        float iou = inter / ua;
        if (iou > best) { best = iou; bi = j; }   // strict > : first max wins
    }
    iou_max = best;
    arg = bi;
    float lab = ann[bi * 5 + 4];
    tgt = (best >= 0.5f) ? lab : ((best < 0.4f) ? NCLSF : -1.0f);
}

__device__ __forceinline__ int code_of(float tgt) {
    int vld = (tgt != -1.0f) ? 4 : 0;
    int tix = (tgt == NCLSF) ? 3 : ((tgt == 2.0f) ? 2 : ((tgt == 1.0f) ? 1 : 0));
    return tix | vld;
}

// Kernel A: assignment codes for every (b,a) + regression loss partials.
__global__ __launch_bounds__(256) void k_assign(const float* __restrict__ annotations,
                                                const float* __restrict__ regressions,
                                                float* __restrict__ ws,
                                                unsigned char* __restrict__ codes) {
    int idx = blockIdx.x * 256 + threadIdx.x;
    int b = idx / NA;           // NA % 256 == 0 -> whole block in one image
    int a = idx - b * NA;
    const float* ann = annotations + b * NG * 5;
    float tgt; int arg; float im;
    assign_anchor(ann, a, tgt, arg, im);
    if (codes) codes[idx] = (unsigned char)code_of(tgt);

    float sl1 = 0.0f, posf = 0.0f;
    if (im >= 0.5f) {
        posf = 1.0f;
        float ax0, ay0, ax1, ay1;
        anchor_of(a, ax0, ay0, ax1, ay1);
        float aw = ax1 - ax0, ah = ay1 - ay0;
        float acx = ax0 + 0.5f * aw, acy = ay0 + 0.5f * ah;
        const float* bb = ann + arg * 5;
        float rgw = bb[2] - bb[0], rgh = bb[3] - bb[1];
        float gcx = bb[0] + 0.5f * rgw, gcy = bb[1] + 0.5f * rgh;
        float gw = fmaxf(rgw, 1.0f), gh = fmaxf(rgh, 1.0f);
        float t[4];
        t[0] = ((gcx - acx) / aw) / 0.1f;
        t[1] = ((gcy - acy) / ah) / 0.1f;
        t[2] = logf(gw / aw) / 0.2f;
        t[3] = logf(gh / ah) / 0.2f;
        const float* rg = regressions + (size_t)idx * 4;
        #pragma unroll
        for (int k = 0; k < 4; ++k) {
            float diff = fabsf(t[k] - rg[k]);
            sl1 += (diff <= (1.0f / 9.0f)) ? (0.5f * 9.0f * diff * diff)
                                           : (diff - 0.5f / 9.0f);
        }
    }
    #pragma unroll
    for (int s = 1; s < 64; s <<= 1) {
        sl1 += __shfl_xor(sl1, s, 64);
        posf += __shfl_xor(posf, s, 64);
    }
    __shared__ float s_sl1[4], s_np[4];
    int lane = threadIdx.x & 63, wid = threadIdx.x >> 6;
    if (lane == 0) { s_sl1[wid] = sl1; s_np[wid] = posf; }
    __syncthreads();
    if (threadIdx.x == 0) {
        atomicAdd(&ws[WS_REG + b],  s_sl1[0] + s_sl1[1] + s_sl1[2] + s_sl1[3]);
        atomicAdd(&ws[WS_NPOS + b], s_np[0] + s_np[1] + s_np[2] + s_np[3]);
    }
}

// Kernel B: prototype partial sums over support rows. Pure predicated stream.
__global__ __launch_bounds__(256) void k_proto(const float* __restrict__ annotations,
                                               const float* __restrict__ cls,
                                               float* __restrict__ ws,
                                               const unsigned char* __restrict__ codes) {
    const int NCHUNK = (NSUP * NA) / 64;   // 8000
    int lane = threadIdx.x & 63;
    int rg = lane >> 4;
    int zi = (lane & 15) * 4;
    int gwid = (blockIdx.x * blockDim.x + threadIdx.x) >> 6;
    int nw = (gridDim.x * blockDim.x) >> 6;
    float acc[4][4] = {};
    float cnt[4] = {};
    for (int chunk = gwid; chunk < NCHUNK; chunk += nw) {
        int base = chunk * 64;
        int ci_inline = -1;
        if (!codes) {
            int r = base + lane, b = r / NA, a = r - b * NA;
            float tgt; int arg; float im;
            assign_anchor(annotations + b * NG * 5, a, tgt, arg, im);
            int c = code_of(tgt);
            ci_inline = c;
        }
        #pragma unroll
        for (int i = 0; i < 16; ++i) {
            int src = i * 4 + rg;
            int row = base + src;
            int cq = codes ? (int)codes[row] : __shfl(ci_inline, src, 64);
            const float4 v = *reinterpret_cast<const float4*>(
                cls + (size_t)row * NZ + zi);
            #pragma unroll
            for (int c = 0; c < 4; ++c) {
                float sel = (cq == (c | 4)) ? 1.0f : 0.0f;
                acc[c][0] = fmaf(sel, v.x, acc[c][0]);
                acc[c][1] = fmaf(sel, v.y, acc[c][1]);
                acc[c][2] = fmaf(sel, v.z, acc[c][2]);
                acc[c][3] = fmaf(sel, v.w, acc[c][3]);
                if ((lane & 15) == 0) cnt[c] += sel;
            }
        }
    }
    // wave reduce across the 4 groups, then block LDS reduce, then sliced atomics
    __shared__ float s_acc[260];
    for (int t = threadIdx.x; t < 260; t += 256) s_acc[t] = 0.0f;
    __syncthreads();
    #pragma unroll
    for (int c = 0; c < 4; ++c) {
        #pragma unroll
        for (int k = 0; k < 4; ++k) {
            float v = acc[c][k];
            v += __shfl_xor(v, 16, 64);
            v += __shfl_xor(v, 32, 64);
            if (lane < 16) atomicAdd(&s_acc[c * NZ + zi + k], v);
        }
        float cv = cnt[c];
        cv += __shfl_xor(cv, 16, 64);
        cv += __shfl_xor(cv, 32, 64);
        if (lane == 0) atomicAdd(&s_acc[256 + c], cv);
    }
    __syncthreads();
    int slice = blockIdx.x & 3;
    for (int t = threadIdx.x; t < 260; t += 256)
        atomicAdd(&ws[slice * 260 + t], s_acc[t]);
}

// Kernel C: query pass. dists via dot-product trick: softmax(-d) == softmax(2*e.p - |p|^2).
__global__ __launch_bounds__(256) void k_query(const float* __restrict__ annotations,
                                               const float* __restrict__ cls,
                                               float* __restrict__ ws,
                                               const unsigned char* __restrict__ codes) {
    const int NCHUNK = (NQ * NA) / 64;     // 4800
    const int QROW0 = NSUP * NA;           // 512000
    int lane = threadIdx.x & 63;
    int rg = lane >> 4;
    int zi = (lane & 15) * 4;

    // build per-lane proto slice (4 dims per class) + full |p_c|^2 via group reduce
    float p[4][4];
    float q[4];
    #pragma unroll
    for (int c = 0; c < 4; ++c) {
        float cv = 0.0f;
        float s0 = 0.0f, s1 = 0.0f, s2 = 0.0f, s3 = 0.0f;
        #pragma unroll
        for (int s = 0; s < 4; ++s) {
            cv += ws[s * 260 + 256 + c];
            const float4 v = *reinterpret_cast<const float4*>(
                &ws[s * 260 + c * NZ + zi]);
            s0 += v.x; s1 += v.y; s2 += v.z; s3 += v.w;
        }
        cv = fmaxf(cv, 1.0f);
        p[c][0] = s0 / cv; p[c][1] = s1 / cv; p[c][2] = s2 / cv; p[c][3] = s3 / cv;
        float qp = p[c][0]*p[c][0] + p[c][1]*p[c][1] + p[c][2]*p[c][2] + p[c][3]*p[c][3];
        qp += __shfl_xor(qp, 1, 64);
        qp += __shfl_xor(qp, 2, 64);
        qp += __shfl_xor(qp, 4, 64);
        qp += __shfl_xor(qp, 8, 64);
        q[c] = qp;
    }

    int gwid = (blockIdx.x * blockDim.x + threadIdx.x) >> 6;
    int nw = (gridDim.x * blockDim.x) >> 6;
    float clsAcc = 0.0f, npqAcc = 0.0f;
    for (int chunk = gwid; chunk < NCHUNK; chunk += nw) {
        int base = chunk * 64;
        int code_inline = 0;
        if (!codes) {
            int r = base + lane, b = NSUP + r / NA, a = r % NA;
            float tgt; int arg; float im;
            assign_anchor(annotations + b * NG * 5, a, tgt, arg, im);
            code_inline = code_of(tgt);
        }
        #pragma unroll
        for (int i = 0; i < 16; ++i) {
            int src = i * 4 + rg;
            int row = base + src;
            int cq = codes ? (int)codes[QROW0 + row] : __shfl(code_inline, src, 64);
            const float4 e = *reinterpret_cast<const float4*>(
                cls + (size_t)(QROW0 + row) * NZ + zi);
            float d0 = e.x*p[0][0] + e.y*p[0][1] + e.z*p[0][2] + e.w*p[0][3];
            float d1 = e.x*p[1][0] + e.y*p[1][1] + e.z*p[1][2] + e.w*p[1][3];
            float d2 = e.x*p[2][0] + e.y*p[2][1] + e.z*p[2][2] + e.w*p[2][3];
            float d3 = e.x*p[3][0] + e.y*p[3][1] + e.z*p[3][2] + e.w*p[3][3];
            #pragma unroll
            for (int s = 1; s < 16; s <<= 1) {
                d0 += __shfl_xor(d0, s, 64);
                d1 += __shfl_xor(d1, s, 64);
                d2 += __shfl_xor(d2, s, 64);
                d3 += __shfl_xor(d3, s, 64);
            }
            float l0 = 2.0f * d0 - q[0];
            float l1 = 2.0f * d1 - q[1];
            float l2 = 2.0f * d2 - q[2];
            float l3 = 2.0f * d3 - q[3];
            float m = fmaxf(fmaxf(l0, l1), fmaxf(l2, l3));
            float ex0 = expf(l0 - m);
            float ex1 = expf(l1 - m);
            float ex2 = expf(l2 - m);
            float ex3 = expf(l3 - m);
            float ssum = ex0 + ex1 + ex2 + ex3;
            int tq = cq & 3;
            float pnum = (tq == 0) ? ex0 : (tq == 1) ? ex1 : (tq == 2) ? ex2 : ex3;
            float prob = pnum / ssum;
            float om = 1.0f - prob;
            float term = -0.25f * om * om * logf(prob);
            if ((lane & 15) == 0 && (cq & 4)) {
                clsAcc += term;
                if (tq != 3) npqAcc += 1.0f;
            }
        }
    }
    // block reduce then sliced atomics
    #pragma unroll
    for (int s = 1; s < 64; s <<= 1) {
        clsAcc += __shfl_xor(clsAcc, s, 64);
        npqAcc += __shfl_xor(npqAcc, s, 64);
    }
    __shared__ float s_cls[4], s_npq[4];
    int wid = threadIdx.x >> 6;
    if (lane == 0) { s_cls[wid] = clsAcc; s_npq[wid] = npqAcc; }
    __syncthreads();
    if (threadIdx.x == 0) {
        int slice = blockIdx.x & 3;
        atomicAdd(&ws[WS_CLS + slice], s_cls[0] + s_cls[1] + s_cls[2] + s_cls[3]);
        atomicAdd(&ws[WS_NPQ + slice], s_npq[0] + s_npq[1] + s_npq[2] + s_npq[3]);
    }
}

__global__ void k_final(const float* __restrict__ ws, float* __restrict__ out) {
    if (threadIdx.x == 0 && blockIdx.x == 0) {
        float cs = ws[WS_CLS] + ws[WS_CLS+1] + ws[WS_CLS+2] + ws[WS_CLS+3];
        float nq = ws[WS_NPQ] + ws[WS_NPQ+1] + ws[WS_NPQ+2] + ws[WS_NPQ+3];
        float clsl = cs / fmaxf(nq, 1.0f);
        float rs = 0.0f;
        #pragma unroll
        for (int b = 0; b < NB; ++b) {
            float np_ = ws[WS_NPOS + b];
            float sv = ws[WS_REG + b];
            rs += (np_ > 0.0f) ? (sv / fmaxf(4.0f * np_, 1.0f)) : 0.0f;
        }
        out[0] = clsl;          // cls_loss
        out[1] = rs * 0.125f;   // reg_loss (mean over 8 images)
    }
}

extern "C" void kernel_launch(void* const* d_in, const int* in_sizes, int n_in,
                              void* d_out, int out_size, void* d_ws, size_t ws_size,
                              hipStream_t stream) {
    const float* classifications = (const float*)d_in[0];
    const float* regressions    = (const float*)d_in[1];
    // d_in[2] (anchors) is analytic: [4j, 4i, 4j+4, 4i+4] — recomputed on device.
    const float* annotations    = (const float*)d_in[3];
    float* ws  = (float*)d_ws;
    float* out = (float*)d_out;
    unsigned char* codes = (ws_size >= (size_t)WS_BYTES_NEEDED)
                         ? ((unsigned char*)d_ws + CODES_OFF) : nullptr;

    hipMemsetAsync(d_ws, 0, 8192, stream);   // float scratch region only
    k_assign<<<(NB * NA) / 256, 256, 0, stream>>>(annotations, regressions, ws, codes);
    k_proto<<<1000, 256, 0, stream>>>(annotations, classifications, ws, codes);
    k_query<<<1200, 256, 0, stream>>>(annotations, classifications, ws, codes);
    k_final<<<1, 64, 0, stream>>>(ws, out);
}

// Round 3
// 175.413 us; speedup vs baseline: 2.2216x; 1.1006x over previous
//
#include <hip/hip_runtime.h>

#define NB 8
#define NA 102400
#define NGRID 320
#define NG 16
#define NZ 64
#define NSUP 5
#define NQ 3
#define NCLSF 80.0f
#define NSLICE 8

// ws float layout:
//  slice s in [0,8): base s*260:
//    [c*64+d] protoSum partials (256), [256+c] protoCnt partials (4)
//  [2080..2087] regSum[b]
//  [2088..2095] nposSum[b]
//  [2096..2099] clsSum slices (4)
//  [2100..2103] npqSum slices (4)
// byte offset 16384: uint8 codes[NB*NA] (bits0-1 class idx, bit2 valid)
#define WS_REG  2080
#define WS_NPOS 2088
#define WS_CLS  2096
#define WS_NPQ  2100
#define CODES_OFF 16384
#define WS_BYTES_NEEDED (CODES_OFF + NB * NA)

__device__ __forceinline__ void anchor_of(int a, float& ax0, float& ay0,
                                          float& ax1, float& ay1) {
    int i = a / NGRID;
    int j = a - i * NGRID;
    ax0 = (float)j * 4.0f;
    ay0 = (float)i * 4.0f;
    ax1 = ax0 + 4.0f;
    ay1 = ay0 + 4.0f;
}

// iou over 16 boxes, FIRST-max argmax (strict >), target assignment.
__device__ __forceinline__ void assign_anchor(const float* ann, int a,
                                              float& tgt, int& arg, float& iou_max) {
    float ax0, ay0, ax1, ay1;
    anchor_of(a, ax0, ay0, ax1, ay1);
    float aw = ax1 - ax0, ah = ay1 - ay0;
    float aarea = aw * ah;
    float best = -1.0f;
    int bi = 0;
    #pragma unroll
    for (int j = 0; j < NG; ++j) {
        float bx0 = ann[j * 5 + 0], by0 = ann[j * 5 + 1];
        float bx1 = ann[j * 5 + 2], by1 = ann[j * 5 + 3];
        float iw = fmaxf(fminf(ax1, bx1) - fmaxf(ax0, bx0), 0.0f);
        float ih = fmaxf(fminf(ay1, by1) - fmaxf(ay0, by0), 0.0f);
        float inter = iw * ih;
        float area = (bx1 - bx0) * (by1 - by0);
        float ua = fmaxf(aarea + area - inter, 1e-8f);
        float iou = inter / ua;
        if (iou > best) { best = iou; bi = j; }
    }
    iou_max = best;
    arg = bi;
    float lab = ann[bi * 5 + 4];
    tgt = (best >= 0.5f) ? lab : ((best < 0.4f) ? NCLSF : -1.0f);
}

__device__ __forceinline__ int code_of(float tgt) {
    int vld = (tgt != -1.0f) ? 4 : 0;
    int tix = (tgt == NCLSF) ? 3 : ((tgt == 2.0f) ? 2 : ((tgt == 1.0f) ? 1 : 0));
    return tix | vld;
}

// Kernel A: codes for every (b,a), reg-loss partials, support proto-counts.
__global__ __launch_bounds__(256) void fl_assign(const float* __restrict__ annotations,
                                                 const float* __restrict__ regressions,
                                                 float* __restrict__ ws,
                                                 unsigned char* __restrict__ codes) {
    __shared__ float s_ann[NG * 5];
    __shared__ float s_sl1[4], s_np[4];
    __shared__ int s_cnt[4];
    int idx = blockIdx.x * 256 + threadIdx.x;
    int b = idx / NA;                  // NA % 256 == 0: block-uniform
    int a = idx - b * NA;
    if (threadIdx.x < NG * 5) s_ann[threadIdx.x] = annotations[b * NG * 5 + threadIdx.x];
    if (threadIdx.x < 4) s_cnt[threadIdx.x] = 0;
    __syncthreads();

    float tgt; int arg; float im;
    assign_anchor(s_ann, a, tgt, arg, im);
    int code = code_of(tgt);
    if (codes) codes[idx] = (unsigned char)code;

    float sl1 = 0.0f, posf = 0.0f;
    if (im >= 0.5f) {
        posf = 1.0f;
        float ax0, ay0, ax1, ay1;
        anchor_of(a, ax0, ay0, ax1, ay1);
        float aw = ax1 - ax0, ah = ay1 - ay0;
        float acx = ax0 + 0.5f * aw, acy = ay0 + 0.5f * ah;
        const float* bb = s_ann + arg * 5;
        float rgw = bb[2] - bb[0], rgh = bb[3] - bb[1];
        float gcx = bb[0] + 0.5f * rgw, gcy = bb[1] + 0.5f * rgh;
        float gw = fmaxf(rgw, 1.0f), gh = fmaxf(rgh, 1.0f);
        float t0 = ((gcx - acx) / aw) / 0.1f;
        float t1 = ((gcy - acy) / ah) / 0.1f;
        float t2 = logf(gw / aw) / 0.2f;
        float t3 = logf(gh / ah) / 0.2f;
        const float4 rg4 = *reinterpret_cast<const float4*>(regressions + (size_t)idx * 4);
        float d0 = fabsf(t0 - rg4.x), d1 = fabsf(t1 - rg4.y);
        float d2 = fabsf(t2 - rg4.z), d3 = fabsf(t3 - rg4.w);
        sl1 += (d0 <= (1.0f/9.0f)) ? (4.5f * d0 * d0) : (d0 - 0.5f/9.0f);
        sl1 += (d1 <= (1.0f/9.0f)) ? (4.5f * d1 * d1) : (d1 - 0.5f/9.0f);
        sl1 += (d2 <= (1.0f/9.0f)) ? (4.5f * d2 * d2) : (d2 - 0.5f/9.0f);
        sl1 += (d3 <= (1.0f/9.0f)) ? (4.5f * d3 * d3) : (d3 - 0.5f/9.0f);
    }
    int lane = threadIdx.x & 63, wid = threadIdx.x >> 6;
    #pragma unroll
    for (int s = 1; s < 64; s <<= 1) {
        sl1 += __shfl_xor(sl1, s, 64);
        posf += __shfl_xor(posf, s, 64);
    }
    if (lane == 0) { s_sl1[wid] = sl1; s_np[wid] = posf; }

    if (b < NSUP) {   // block-uniform: support proto counts via ballot
        #pragma unroll
        for (int c = 0; c < 4; ++c) {
            unsigned long long m = __ballot(code == (c | 4));
            if (lane == 0) atomicAdd(&s_cnt[c], (int)__popcll(m));
        }
    }
    __syncthreads();
    if (threadIdx.x == 0) {
        atomicAdd(&ws[WS_REG + b],  s_sl1[0] + s_sl1[1] + s_sl1[2] + s_sl1[3]);
        atomicAdd(&ws[WS_NPOS + b], s_np[0] + s_np[1] + s_np[2] + s_np[3]);
    }
    if (b < NSUP && threadIdx.x < 4 && s_cnt[threadIdx.x] > 0)
        atomicAdd(&ws[(blockIdx.x & (NSLICE - 1)) * 260 + 256 + threadIdx.x],
                  (float)s_cnt[threadIdx.x]);
}

// Kernel B: prototype sums over support rows. Batched loads, no cross-lane ops.
__global__ __launch_bounds__(256, 2) void fl_proto(const float* __restrict__ annotations,
                                                   const float* __restrict__ cls,
                                                   float* __restrict__ ws,
                                                   const unsigned char* __restrict__ codes) {
    const int NCHUNK = (NSUP * NA) / 64;   // 8000
    int lane = threadIdx.x & 63;
    int rg = lane >> 4;
    int li = lane & 15;
    int gwid = (blockIdx.x * 256 + threadIdx.x) >> 6;
    int nw = (gridDim.x * 256) >> 6;
    float acc[4][4] = {};
    for (int chunk = gwid; chunk < NCHUNK; chunk += nw) {
        int base = chunk * 64;
        if (codes) {
            const uint4* cw = (const uint4*)(codes + base);
            uint4 w0 = cw[0], w1 = cw[1], w2 = cw[2], w3 = cw[3];
            float4 v[16];
            const float4* P = (const float4*)cls + ((size_t)(base + rg) * 16 + li);
            #pragma unroll
            for (int i = 0; i < 16; ++i) v[i] = P[(size_t)i * 64];
            unsigned wd[16] = {w0.x, w0.y, w0.z, w0.w, w1.x, w1.y, w1.z, w1.w,
                               w2.x, w2.y, w2.z, w2.w, w3.x, w3.y, w3.z, w3.w};
            int sh = rg * 8;
            #pragma unroll
            for (int i = 0; i < 16; ++i) {
                int cq = (int)((wd[i] >> sh) & 0xffu);
                #pragma unroll
                for (int c = 0; c < 4; ++c) {
                    float sel = (cq == (c | 4)) ? 1.0f : 0.0f;
                    acc[c][0] = fmaf(sel, v[i].x, acc[c][0]);
                    acc[c][1] = fmaf(sel, v[i].y, acc[c][1]);
                    acc[c][2] = fmaf(sel, v[i].z, acc[c][2]);
                    acc[c][3] = fmaf(sel, v[i].w, acc[c][3]);
                }
            }
        } else {        // fallback: inline assignment
            int r = base + lane, b = r / NA, a = r - b * NA;
            float tgt; int arg; float im;
            assign_anchor(annotations + b * NG * 5, a, tgt, arg, im);
            int ci = code_of(tgt);
            #pragma unroll
            for (int i = 0; i < 16; ++i) {
                int cq = __shfl(ci, i * 4 + rg, 64);
                const float4 v = *((const float4*)cls + ((size_t)(base + i * 4 + rg) * 16 + li));
                #pragma unroll
                for (int c = 0; c < 4; ++c) {
                    float sel = (cq == (c | 4)) ? 1.0f : 0.0f;
                    acc[c][0] = fmaf(sel, v.x, acc[c][0]);
                    acc[c][1] = fmaf(sel, v.y, acc[c][1]);
                    acc[c][2] = fmaf(sel, v.z, acc[c][2]);
                    acc[c][3] = fmaf(sel, v.w, acc[c][3]);
                }
            }
        }
    }
    __shared__ float s_acc[256];
    s_acc[threadIdx.x] = 0.0f;
    __syncthreads();
    int zi = li * 4;
    #pragma unroll
    for (int c = 0; c < 4; ++c) {
        #pragma unroll
        for (int k = 0; k < 4; ++k) {
            float vv = acc[c][k];
            vv += __shfl_xor(vv, 16, 64);
            vv += __shfl_xor(vv, 32, 64);
            if (lane < 16) atomicAdd(&s_acc[c * 64 + zi + k], vv);
        }
    }
    __syncthreads();
    atomicAdd(&ws[(blockIdx.x & (NSLICE - 1)) * 260 + threadIdx.x], s_acc[threadIdx.x]);
}

// Kernel C: query pass. Batched loads; dists via 2*e.p - |p|^2.
__global__ __launch_bounds__(256, 2) void fl_query(const float* __restrict__ annotations,
                                                   const float* __restrict__ cls,
                                                   float* __restrict__ ws,
                                                   const unsigned char* __restrict__ codes) {
    const int NCHUNK = (NQ * NA) / 64;     // 4800
    const int QROW0 = NSUP * NA;           // 512000
    int lane = threadIdx.x & 63;
    int rg = lane >> 4;
    int li = lane & 15;
    int zi = li * 4;

    float p[4][4], q[4];
    #pragma unroll
    for (int c = 0; c < 4; ++c) {
        float cv = 0.0f;
        float s0 = 0.0f, s1 = 0.0f, s2 = 0.0f, s3 = 0.0f;
        #pragma unroll
        for (int s = 0; s < NSLICE; ++s) {
            cv += ws[s * 260 + 256 + c];
            const float4 v = *reinterpret_cast<const float4*>(&ws[s * 260 + c * 64 + zi]);
            s0 += v.x; s1 += v.y; s2 += v.z; s3 += v.w;
        }
        cv = fmaxf(cv, 1.0f);
        p[c][0] = s0 / cv; p[c][1] = s1 / cv; p[c][2] = s2 / cv; p[c][3] = s3 / cv;
        float qp = p[c][0]*p[c][0] + p[c][1]*p[c][1] + p[c][2]*p[c][2] + p[c][3]*p[c][3];
        qp += __shfl_xor(qp, 1, 64);
        qp += __shfl_xor(qp, 2, 64);
        qp += __shfl_xor(qp, 4, 64);
        qp += __shfl_xor(qp, 8, 64);
        q[c] = qp;
    }

    int gwid = (blockIdx.x * 256 + threadIdx.x) >> 6;
    int nw = (gridDim.x * 256) >> 6;
    float clsAcc = 0.0f, npqAcc = 0.0f;
    for (int chunk = gwid; chunk < NCHUNK; chunk += nw) {
        int base = chunk * 64;
        unsigned wd[16];
        int ci_inline = 0;
        if (codes) {
            const uint4* cw = (const uint4*)(codes + QROW0 + base);
            uint4 w0 = cw[0], w1 = cw[1], w2 = cw[2], w3 = cw[3];
            wd[0]=w0.x; wd[1]=w0.y; wd[2]=w0.z; wd[3]=w0.w;
            wd[4]=w1.x; wd[5]=w1.y; wd[6]=w1.z; wd[7]=w1.w;
            wd[8]=w2.x; wd[9]=w2.y; wd[10]=w2.z; wd[11]=w2.w;
            wd[12]=w3.x; wd[13]=w3.y; wd[14]=w3.z; wd[15]=w3.w;
        } else {
            int r = base + lane, b = NSUP + r / NA, a = r % NA;
            float tgt; int arg; float im;
            assign_anchor(annotations + b * NG * 5, a, tgt, arg, im);
            ci_inline = code_of(tgt);
        }
        float4 v[16];
        const float4* P = (const float4*)cls + ((size_t)(QROW0 + base + rg) * 16 + li);
        #pragma unroll
        for (int i = 0; i < 16; ++i) v[i] = P[(size_t)i * 64];
        int sh = rg * 8;
        #pragma unroll
        for (int i = 0; i < 16; ++i) {
            int cq = codes ? (int)((wd[i] >> sh) & 0xffu)
                           : __shfl(ci_inline, i * 4 + rg, 64);
            float d0 = v[i].x*p[0][0] + v[i].y*p[0][1] + v[i].z*p[0][2] + v[i].w*p[0][3];
            float d1 = v[i].x*p[1][0] + v[i].y*p[1][1] + v[i].z*p[1][2] + v[i].w*p[1][3];
            float d2 = v[i].x*p[2][0] + v[i].y*p[2][1] + v[i].z*p[2][2] + v[i].w*p[2][3];
            float d3 = v[i].x*p[3][0] + v[i].y*p[3][1] + v[i].z*p[3][2] + v[i].w*p[3][3];
            #pragma unroll
            for (int s = 1; s < 16; s <<= 1) {
                d0 += __shfl_xor(d0, s, 64);
                d1 += __shfl_xor(d1, s, 64);
                d2 += __shfl_xor(d2, s, 64);
                d3 += __shfl_xor(d3, s, 64);
            }
            float l0 = 2.0f * d0 - q[0];
            float l1 = 2.0f * d1 - q[1];
            float l2 = 2.0f * d2 - q[2];
            float l3 = 2.0f * d3 - q[3];
            float m = fmaxf(fmaxf(l0, l1), fmaxf(l2, l3));
            float ex0 = expf(l0 - m);
            float ex1 = expf(l1 - m);
            float ex2 = expf(l2 - m);
            float ex3 = expf(l3 - m);
            float ssum = ex0 + ex1 + ex2 + ex3;
            int tq = cq & 3;
            float pnum = (tq == 0) ? ex0 : (tq == 1) ? ex1 : (tq == 2) ? ex2 : ex3;
            float prob = pnum / ssum;
            float om = 1.0f - prob;
            float term = -0.25f * om * om * logf(prob);
            if (li == 0 && (cq & 4)) {
                clsAcc += term;
                if (tq != 3) npqAcc += 1.0f;
            }
        }
    }
    #pragma unroll
    for (int s = 1; s < 64; s <<= 1) {
        clsAcc += __shfl_xor(clsAcc, s, 64);
        npqAcc += __shfl_xor(npqAcc, s, 64);
    }
    __shared__ float s_cls[4], s_npq[4];
    int wid = threadIdx.x >> 6;
    if (lane == 0) { s_cls[wid] = clsAcc; s_npq[wid] = npqAcc; }
    __syncthreads();
    if (threadIdx.x == 0) {
        int slice = blockIdx.x & 3;
        atomicAdd(&ws[WS_CLS + slice], s_cls[0] + s_cls[1] + s_cls[2] + s_cls[3]);
        atomicAdd(&ws[WS_NPQ + slice], s_npq[0] + s_npq[1] + s_npq[2] + s_npq[3]);
    }
}

__global__ void fl_final(const float* __restrict__ ws, float* __restrict__ out) {
    if (threadIdx.x == 0 && blockIdx.x == 0) {
        float cs = ws[WS_CLS] + ws[WS_CLS+1] + ws[WS_CLS+2] + ws[WS_CLS+3];
        float nq = ws[WS_NPQ] + ws[WS_NPQ+1] + ws[WS_NPQ+2] + ws[WS_NPQ+3];
        float clsl = cs / fmaxf(nq, 1.0f);
        float rs = 0.0f;
        #pragma unroll
        for (int b = 0; b < NB; ++b) {
            float np_ = ws[WS_NPOS + b];
            float sv = ws[WS_REG + b];
            rs += (np_ > 0.0f) ? (sv / fmaxf(4.0f * np_, 1.0f)) : 0.0f;
        }
        out[0] = clsl;
        out[1] = rs * 0.125f;
    }
}

extern "C" void kernel_launch(void* const* d_in, const int* in_sizes, int n_in,
                              void* d_out, int out_size, void* d_ws, size_t ws_size,
                              hipStream_t stream) {
    const float* classifications = (const float*)d_in[0];
    const float* regressions    = (const float*)d_in[1];
    // d_in[2] (anchors) analytic: [4j, 4i, 4j+4, 4i+4] — recomputed on device.
    const float* annotations    = (const float*)d_in[3];
    float* ws  = (float*)d_ws;
    float* out = (float*)d_out;
    unsigned char* codes = (ws_size >= (size_t)WS_BYTES_NEEDED)
                         ? ((unsigned char*)d_ws + CODES_OFF) : nullptr;

    hipMemsetAsync(d_ws, 0, CODES_OFF, stream);
    fl_assign<<<(NB * NA) / 256, 256, 0, stream>>>(annotations, regressions, ws, codes);
    fl_proto<<<2000, 256, 0, stream>>>(annotations, classifications, ws, codes);
    fl_query<<<1200, 256, 0, stream>>>(annotations, classifications, ws, codes);
    fl_final<<<1, 64, 0, stream>>>(ws, out);
}

// Round 4
// 127.091 us; speedup vs baseline: 3.0663x; 1.3802x over previous
//
#include <hip/hip_runtime.h>

#define NB 8
#define NA 102400
#define NGRID 320
#define NG 16
#define NSUP 5
#define NQ 3
#define NCLSF 80.0f
#define NSLICE 8
#define SLS 264                      // slice stride (256 sums + 4 counts + pad)
#define WS_REG   (NSLICE * SLS)      // 2112: regSum[8]
#define WS_NPOS  (WS_REG + NB)       // 2120: nposSum[8]
#define WS_CLS   (WS_NPOS + NB)      // 2128: clsSum slices[4]
#define WS_NPQ   (WS_CLS + 4)        // 2132: npqSum slices[4]
#define WS_FLOATS (WS_NPQ + 4)       // 2136 floats = 8544 B
#define BPI 400                      // blocks per image; 4 chunks(64 rows) per block

__device__ __forceinline__ void anchor_of(int a, float& ax0, float& ay0,
                                          float& ax1, float& ay1) {
    int i = a / NGRID;
    int j = a - i * NGRID;
    ax0 = (float)j * 4.0f;
    ay0 = (float)i * 4.0f;
    ax1 = ax0 + 4.0f;
    ay1 = ay0 + 4.0f;
}

// iou over 16 boxes, FIRST-max argmax (strict >), target assignment.
__device__ __forceinline__ void assign_anchor(const float* ann, int a,
                                              float& tgt, int& arg, float& iou_max) {
    float ax0, ay0, ax1, ay1;
    anchor_of(a, ax0, ay0, ax1, ay1);
    float aw = ax1 - ax0, ah = ay1 - ay0;
    float aarea = aw * ah;
    float best = -1.0f;
    int bi = 0;
    #pragma unroll
    for (int j = 0; j < NG; ++j) {
        float bx0 = ann[j * 5 + 0], by0 = ann[j * 5 + 1];
        float bx1 = ann[j * 5 + 2], by1 = ann[j * 5 + 3];
        float iw = fmaxf(fminf(ax1, bx1) - fmaxf(ax0, bx0), 0.0f);
        float ih = fmaxf(fminf(ay1, by1) - fmaxf(ay0, by0), 0.0f);
        float inter = iw * ih;
        float area = (bx1 - bx0) * (by1 - by0);
        float ua = fmaxf(aarea + area - inter, 1e-8f);
        float iou = inter / ua;
        if (iou > best) { best = iou; bi = j; }
    }
    iou_max = best;
    arg = bi;
    float lab = ann[bi * 5 + 4];
    tgt = (best >= 0.5f) ? lab : ((best < 0.4f) ? NCLSF : -1.0f);
}

__device__ __forceinline__ int code_of(float tgt) {
    int vld = (tgt != -1.0f) ? 4 : 0;
    int tix = (tgt == NCLSF) ? 3 : ((tgt == 2.0f) ? 2 : ((tgt == 1.0f) ? 1 : 0));
    return tix | vld;
}

// Per-lane reg-loss partial for this lane's own row (only if positive).
__device__ __forceinline__ void reg_partial(const float* ann, int a, int arg, float im,
                                            const float* __restrict__ regressions,
                                            size_t row, float& sl1, float& posf) {
    sl1 = 0.0f; posf = 0.0f;
    if (im >= 0.5f) {
        posf = 1.0f;
        float ax0, ay0, ax1, ay1;
        anchor_of(a, ax0, ay0, ax1, ay1);
        float aw = ax1 - ax0, ah = ay1 - ay0;
        float acx = ax0 + 0.5f * aw, acy = ay0 + 0.5f * ah;
        const float* bb = ann + arg * 5;
        float rgw = bb[2] - bb[0], rgh = bb[3] - bb[1];
        float gcx = bb[0] + 0.5f * rgw, gcy = bb[1] + 0.5f * rgh;
        float gw = fmaxf(rgw, 1.0f), gh = fmaxf(rgh, 1.0f);
        float t0 = ((gcx - acx) / aw) / 0.1f;
        float t1 = ((gcy - acy) / ah) / 0.1f;
        float t2 = logf(gw / aw) / 0.2f;
        float t3 = logf(gh / ah) / 0.2f;
        const float4 rg4 = *reinterpret_cast<const float4*>(regressions + row * 4);
        float d0 = fabsf(t0 - rg4.x), d1 = fabsf(t1 - rg4.y);
        float d2 = fabsf(t2 - rg4.z), d3 = fabsf(t3 - rg4.w);
        sl1 += (d0 <= (1.0f/9.0f)) ? (4.5f * d0 * d0) : (d0 - 0.5f/9.0f);
        sl1 += (d1 <= (1.0f/9.0f)) ? (4.5f * d1 * d1) : (d1 - 0.5f/9.0f);
        sl1 += (d2 <= (1.0f/9.0f)) ? (4.5f * d2 * d2) : (d2 - 0.5f/9.0f);
        sl1 += (d3 <= (1.0f/9.0f)) ? (4.5f * d3 * d3) : (d3 - 0.5f/9.0f);
    }
}

// Support images: inline assignment + prototype sums/counts + reg partials.
// Block = 4 chunks of 64 rows, all in image b = blockIdx.x / BPI.
__global__ __launch_bounds__(256, 3) void fl_proto(const float* __restrict__ annotations,
                                                   const float* __restrict__ cls,
                                                   const float* __restrict__ regressions,
                                                   float* __restrict__ ws) {
    __shared__ float s_ann[NG * 5];
    __shared__ float s_acc[256];
    __shared__ float s_sl1[4], s_np[4];
    __shared__ int   s_cnt[4];
    int b    = blockIdx.x / BPI;
    int cb   = blockIdx.x - b * BPI;
    int wid  = threadIdx.x >> 6;
    int lane = threadIdx.x & 63;
    int rg   = lane >> 4, li = lane & 15, zi = li * 4;
    int chunk = cb * 4 + wid;                      // 0..1599 within image
    size_t row0 = (size_t)b * NA + (size_t)chunk * 64;

    // 1) issue the 16 streaming loads (16 KB/wave in flight)
    float4 v[16];
    const float4* P = (const float4*)cls + (row0 + rg) * 16 + li;
    #pragma unroll
    for (int i = 0; i < 16; ++i) v[i] = P[(size_t)i * 64];

    // 2) stage annotations; zero block accumulators
    if (threadIdx.x < NG * 5) s_ann[threadIdx.x] = annotations[b * NG * 5 + threadIdx.x];
    s_acc[threadIdx.x] = 0.0f;
    if (threadIdx.x < 4) s_cnt[threadIdx.x] = 0;
    __syncthreads();

    // 3) per-lane assignment (hides load latency)
    int a = chunk * 64 + lane;
    float tgt; int arg; float im;
    assign_anchor(s_ann, a, tgt, arg, im);
    int ci = code_of(tgt);

    // 4) reg-loss partial for own row
    float sl1, posf;
    reg_partial(s_ann, a, arg, im, regressions, row0 + lane, sl1, posf);
    #pragma unroll
    for (int s = 1; s < 64; s <<= 1) {
        sl1  += __shfl_xor(sl1, s, 64);
        posf += __shfl_xor(posf, s, 64);
    }
    if (lane == 0) { s_sl1[wid] = sl1; s_np[wid] = posf; }

    // 5) prototype counts (support only)
    #pragma unroll
    for (int c = 0; c < 4; ++c) {
        unsigned long long m = __ballot(ci == (c | 4));
        if (lane == 0) atomicAdd(&s_cnt[c], (int)__popcll(m));
    }

    // 6) predicated accumulate of the 16 row-slices
    float acc[4][4] = {};
    #pragma unroll
    for (int i = 0; i < 16; ++i) {
        int cq = __shfl(ci, 4 * i + rg, 64);       // code of row row0+rg+4i
        #pragma unroll
        for (int c = 0; c < 4; ++c) {
            float sel = (cq == (c | 4)) ? 1.0f : 0.0f;
            acc[c][0] = fmaf(sel, v[i].x, acc[c][0]);
            acc[c][1] = fmaf(sel, v[i].y, acc[c][1]);
            acc[c][2] = fmaf(sel, v[i].z, acc[c][2]);
            acc[c][3] = fmaf(sel, v[i].w, acc[c][3]);
        }
    }
    // 7) rg-group reduce -> block LDS -> sliced global atomics
    #pragma unroll
    for (int c = 0; c < 4; ++c) {
        #pragma unroll
        for (int k = 0; k < 4; ++k) {
            float vv = acc[c][k];
            vv += __shfl_xor(vv, 16, 64);
            vv += __shfl_xor(vv, 32, 64);
            if (lane < 16) atomicAdd(&s_acc[c * 64 + zi + k], vv);
        }
    }
    __syncthreads();
    int slice = blockIdx.x & (NSLICE - 1);
    atomicAdd(&ws[slice * SLS + threadIdx.x], s_acc[threadIdx.x]);
    if (threadIdx.x < 4 && s_cnt[threadIdx.x] > 0)
        atomicAdd(&ws[slice * SLS + 256 + threadIdx.x], (float)s_cnt[threadIdx.x]);
    if (threadIdx.x == 0) {
        atomicAdd(&ws[WS_REG + b],  s_sl1[0] + s_sl1[1] + s_sl1[2] + s_sl1[3]);
        atomicAdd(&ws[WS_NPOS + b], s_np[0] + s_np[1] + s_np[2] + s_np[3]);
    }
}

// Query images: inline assignment + focal terms + reg partials.
__global__ __launch_bounds__(256, 3) void fl_query(const float* __restrict__ annotations,
                                                   const float* __restrict__ cls,
                                                   const float* __restrict__ regressions,
                                                   float* __restrict__ ws) {
    __shared__ float s_ann[NG * 5];
    __shared__ float s_cls[4], s_npq[4], s_sl1[4], s_np[4];
    int qb   = blockIdx.x / BPI;
    int b    = NSUP + qb;
    int cb   = blockIdx.x - qb * BPI;
    int wid  = threadIdx.x >> 6;
    int lane = threadIdx.x & 63;
    int rg   = lane >> 4, li = lane & 15, zi = li * 4;
    int chunk = cb * 4 + wid;
    size_t row0 = (size_t)b * NA + (size_t)chunk * 64;

    // 1) issue the 16 streaming loads
    float4 v[16];
    const float4* P = (const float4*)cls + (row0 + rg) * 16 + li;
    #pragma unroll
    for (int i = 0; i < 16; ++i) v[i] = P[(size_t)i * 64];

    if (threadIdx.x < NG * 5) s_ann[threadIdx.x] = annotations[b * NG * 5 + threadIdx.x];
    __syncthreads();

    // 2) build per-lane proto slice + |p|^2 (reads 8.4 KB ws, L2-hot)
    float p[4][4], q[4];
    #pragma unroll
    for (int c = 0; c < 4; ++c) {
        float cv = 0.0f, s0 = 0.0f, s1 = 0.0f, s2 = 0.0f, s3 = 0.0f;
        #pragma unroll
        for (int s = 0; s < NSLICE; ++s) {
            cv += ws[s * SLS + 256 + c];
            const float4 u = *reinterpret_cast<const float4*>(&ws[s * SLS + c * 64 + zi]);
            s0 += u.x; s1 += u.y; s2 += u.z; s3 += u.w;
        }
        cv = fmaxf(cv, 1.0f);
        p[c][0] = s0 / cv; p[c][1] = s1 / cv; p[c][2] = s2 / cv; p[c][3] = s3 / cv;
        float qp = p[c][0]*p[c][0] + p[c][1]*p[c][1] + p[c][2]*p[c][2] + p[c][3]*p[c][3];
        qp += __shfl_xor(qp, 1, 64);
        qp += __shfl_xor(qp, 2, 64);
        qp += __shfl_xor(qp, 4, 64);
        qp += __shfl_xor(qp, 8, 64);
        q[c] = qp;
    }

    // 3) per-lane assignment + reg partial
    int a = chunk * 64 + lane;
    float tgt; int arg; float im;
    assign_anchor(s_ann, a, tgt, arg, im);
    int code = code_of(tgt);
    float sl1, posf;
    reg_partial(s_ann, a, arg, im, regressions, row0 + lane, sl1, posf);

    // 4) focal terms over the 16 row-slices
    float clsAcc = 0.0f, npqAcc = 0.0f;
    #pragma unroll
    for (int i = 0; i < 16; ++i) {
        int cq = __shfl(code, 4 * i + rg, 64);
        float d0 = v[i].x*p[0][0] + v[i].y*p[0][1] + v[i].z*p[0][2] + v[i].w*p[0][3];
        float d1 = v[i].x*p[1][0] + v[i].y*p[1][1] + v[i].z*p[1][2] + v[i].w*p[1][3];
        float d2 = v[i].x*p[2][0] + v[i].y*p[2][1] + v[i].z*p[2][2] + v[i].w*p[2][3];
        float d3 = v[i].x*p[3][0] + v[i].y*p[3][1] + v[i].z*p[3][2] + v[i].w*p[3][3];
        #pragma unroll
        for (int s = 1; s < 16; s <<= 1) {
            d0 += __shfl_xor(d0, s, 64);
            d1 += __shfl_xor(d1, s, 64);
            d2 += __shfl_xor(d2, s, 64);
            d3 += __shfl_xor(d3, s, 64);
        }
        float l0 = 2.0f * d0 - q[0];
        float l1 = 2.0f * d1 - q[1];
        float l2 = 2.0f * d2 - q[2];
        float l3 = 2.0f * d3 - q[3];
        float m = fmaxf(fmaxf(l0, l1), fmaxf(l2, l3));
        float ex0 = expf(l0 - m), ex1 = expf(l1 - m);
        float ex2 = expf(l2 - m), ex3 = expf(l3 - m);
        float ssum = ex0 + ex1 + ex2 + ex3;
        int tq = cq & 3;
        float pnum = (tq == 0) ? ex0 : (tq == 1) ? ex1 : (tq == 2) ? ex2 : ex3;
        float prob = pnum / ssum;
        float om = 1.0f - prob;
        float term = -0.25f * om * om * logf(prob);
        if (li == 0 && (cq & 4)) {
            clsAcc += term;
            if (tq != 3) npqAcc += 1.0f;
        }
    }

    // 5) wave + block reduction, sliced atomics
    #pragma unroll
    for (int s = 1; s < 64; s <<= 1) {
        clsAcc += __shfl_xor(clsAcc, s, 64);
        npqAcc += __shfl_xor(npqAcc, s, 64);
        sl1    += __shfl_xor(sl1, s, 64);
        posf   += __shfl_xor(posf, s, 64);
    }
    if (lane == 0) { s_cls[wid] = clsAcc; s_npq[wid] = npqAcc; s_sl1[wid] = sl1; s_np[wid] = posf; }
    __syncthreads();
    if (threadIdx.x == 0) {
        int slice = blockIdx.x & 3;
        atomicAdd(&ws[WS_CLS + slice], s_cls[0] + s_cls[1] + s_cls[2] + s_cls[3]);
        atomicAdd(&ws[WS_NPQ + slice], s_npq[0] + s_npq[1] + s_npq[2] + s_npq[3]);
        atomicAdd(&ws[WS_REG + b],  s_sl1[0] + s_sl1[1] + s_sl1[2] + s_sl1[3]);
        atomicAdd(&ws[WS_NPOS + b], s_np[0] + s_np[1] + s_np[2] + s_np[3]);
    }
}

__global__ void fl_final(const float* __restrict__ ws, float* __restrict__ out) {
    if (threadIdx.x == 0 && blockIdx.x == 0) {
        float cs = ws[WS_CLS] + ws[WS_CLS+1] + ws[WS_CLS+2] + ws[WS_CLS+3];
        float nq = ws[WS_NPQ] + ws[WS_NPQ+1] + ws[WS_NPQ+2] + ws[WS_NPQ+3];
        float clsl = cs / fmaxf(nq, 1.0f);
        float rs = 0.0f;
        #pragma unroll
        for (int b = 0; b < NB; ++b) {
            float np_ = ws[WS_NPOS + b];
            float sv  = ws[WS_REG + b];
            rs += (np_ > 0.0f) ? (sv / fmaxf(4.0f * np_, 1.0f)) : 0.0f;
        }
        out[0] = clsl;
        out[1] = rs * 0.125f;
    }
}

extern "C" void kernel_launch(void* const* d_in, const int* in_sizes, int n_in,
                              void* d_out, int out_size, void* d_ws, size_t ws_size,
                              hipStream_t stream) {
    const float* classifications = (const float*)d_in[0];
    const float* regressions    = (const float*)d_in[1];
    // d_in[2] (anchors) analytic: [4j, 4i, 4j+4, 4i+4] — recomputed on device.
    const float* annotations    = (const float*)d_in[3];
    float* ws  = (float*)d_ws;
    float* out = (float*)d_out;

    hipMemsetAsync(d_ws, 0, WS_FLOATS * sizeof(float), stream);
    fl_proto<<<NSUP * BPI, 256, 0, stream>>>(annotations, classifications, regressions, ws);
    fl_query<<<NQ * BPI, 256, 0, stream>>>(annotations, classifications, regressions, ws);
    fl_final<<<1, 64, 0, stream>>>(ws, out);
}